// Round 2
// baseline (1080.343 us; speedup 1.0000x reference)
//
#include <hip/hip_runtime.h>
#include <math.h>

// DecoderRNN: output depends ONLY on batch row 0 (reference broadcasts
// totoken_w[idx][0] over the batch). Compute row-0 trajectory with GEMVs.
//
// Dims: H=1024, V=32000, E=18432, B=256, T=15.

#define HDIM 1024
#define VDIM 32000
#define EDIM 18432
#define BDIM 256
#define TSTEPS 15
#define FC_BLOCKS 512

__device__ inline float wave_sum(float v) {
#pragma unroll
  for (int off = 32; off; off >>= 1) v += __shfl_down(v, off, 64);
  return v;
}

template <int NT>
__device__ inline float block_allreduce_sum(float v, float* sm) {
  const int NW = NT / 64;
  int lane = threadIdx.x & 63, wave = threadIdx.x >> 6;
  v = wave_sum(v);
  if (lane == 0) sm[wave] = v;
  __syncthreads();
  float r = (threadIdx.x < NW) ? sm[threadIdx.x] : 0.f;
  if (wave == 0) {
    r = wave_sum(r);
    if (lane == 0) sm[0] = r;
  }
  __syncthreads();
  r = sm[0];
  __syncthreads();  // safe for helper reuse
  return r;
}

// y[r] = relu(dot(W[r,:], x) + b[r]); one block per row.
__global__ __launch_bounds__(256) void gemv_relu(
    const float* __restrict__ W, const float* __restrict__ x,
    const float* __restrict__ b, float* __restrict__ y, int K) {
  __shared__ float sm[4];
  int r = blockIdx.x;
  const float4* wr = (const float4*)(W + (size_t)r * K);
  const float4* xv = (const float4*)x;
  int nk = K >> 2;
  float s = 0.f;
  for (int k = threadIdx.x; k < nk; k += 256) {
    float4 a = wr[k], c = xv[k];
    s = fmaf(a.x, c.x, fmaf(a.y, c.y, fmaf(a.z, c.z, fmaf(a.w, c.w, s))));
  }
  s = block_allreduce_sum<256>(s, sm);
  if (threadIdx.x == 0) y[r] = fmaxf(s + b[r], 0.f);
}

// h = LN(preh)*gh+bh ; c = LN(prec)*gc+bc. Single block, 1024 threads.
__global__ __launch_bounds__(1024) void ln2_kernel(
    const float* __restrict__ ph, const float* __restrict__ pc,
    const float* __restrict__ gh, const float* __restrict__ bh,
    const float* __restrict__ gc, const float* __restrict__ bc,
    float* __restrict__ h, float* __restrict__ c) {
  __shared__ float sm[16];
  int t = threadIdx.x;
  float xh = ph[t];
  float m = block_allreduce_sum<1024>(xh, sm) * (1.f / 1024.f);
  float d = xh - m;
  float var = block_allreduce_sum<1024>(d * d, sm) * (1.f / 1024.f);
  h[t] = d / sqrtf(var + 1e-5f) * gh[t] + bh[t];
  float xc = pc[t];
  float mc = block_allreduce_sum<1024>(xc, sm) * (1.f / 1024.f);
  float dc = xc - mc;
  float vc = block_allreduce_sum<1024>(dc * dc, sm) * (1.f / 1024.f);
  c[t] = dc / sqrtf(vc + 1e-5f) * gc[t] + bc[t];
}

// One block per hidden unit j; wave w computes gate w (rows j + w*H of Wih/Whh).
// Fuses the elementwise LSTM update (thread 0).
__global__ __launch_bounds__(256) void lstm_cell(
    const float* __restrict__ x, const float* __restrict__ hs,
    const float* __restrict__ cs, const float* __restrict__ Wih,
    const float* __restrict__ Whh, const float* __restrict__ bih,
    const float* __restrict__ bhh, float* __restrict__ hout,
    float* __restrict__ cout) {
  __shared__ float g[4];
  int j = blockIdx.x;
  int lane = threadIdx.x & 63, wave = threadIdx.x >> 6;
  size_t row = (size_t)(j + wave * HDIM);
  const float4* wi = (const float4*)(Wih + row * HDIM);
  const float4* wh = (const float4*)(Whh + row * HDIM);
  const float4* xv = (const float4*)x;
  const float4* hv = (const float4*)hs;
  float s = 0.f;
#pragma unroll
  for (int it = 0; it < 4; ++it) {
    int k = lane + (it << 6);
    float4 a = wi[k], c = xv[k];
    s = fmaf(a.x, c.x, fmaf(a.y, c.y, fmaf(a.z, c.z, fmaf(a.w, c.w, s))));
    float4 d = wh[k], e = hv[k];
    s = fmaf(d.x, e.x, fmaf(d.y, e.y, fmaf(d.z, e.z, fmaf(d.w, e.w, s))));
  }
  s = wave_sum(s);
  if (lane == 0) g[wave] = s + bih[row] + bhh[row];
  __syncthreads();
  if (threadIdx.x == 0) {
    float gi = g[0], gf = g[1], gg = g[2], go = g[3];
    float si = 1.f / (1.f + expf(-gi));
    float sf = 1.f / (1.f + expf(-gf));
    float so = 1.f / (1.f + expf(-go));
    float cn = sf * cs[j] + si * tanhf(gg);
    cout[j] = cn;
    hout[j] = so * tanhf(cn);
  }
}

// pred[row] = dot(fc_w[row,:], x) + fc_b[row]; per-block (max, argmax) partial.
__global__ __launch_bounds__(256) void fc_argmax_part(
    const float* __restrict__ W, const float* __restrict__ b,
    const float* __restrict__ x, float* __restrict__ bmax,
    int* __restrict__ bidx) {
  __shared__ float sv[4];
  __shared__ int sidx[4];
  int lane = threadIdx.x & 63, wave = threadIdx.x >> 6;
  int wid = blockIdx.x * 4 + wave;
  const float4* xv = (const float4*)x;
  float best = -3.4e38f;
  int bi = 0x7fffffff;
  for (int row = wid; row < VDIM; row += FC_BLOCKS * 4) {
    const float4* wr = (const float4*)(W + (size_t)row * HDIM);
    float s = 0.f;
#pragma unroll
    for (int it = 0; it < 4; ++it) {
      int k = lane + (it << 6);
      float4 a = wr[k], c = xv[k];
      s = fmaf(a.x, c.x, fmaf(a.y, c.y, fmaf(a.z, c.z, fmaf(a.w, c.w, s))));
    }
    s = wave_sum(s);
    if (lane == 0) {
      s += b[row];
      if (s > best) { best = s; bi = row; }  // rows increase -> first-max kept
    }
  }
  if (lane == 0) { sv[wave] = best; sidx[wave] = bi; }
  __syncthreads();
  if (threadIdx.x == 0) {
    float v = sv[0];
    int ix = sidx[0];
#pragma unroll
    for (int w2 = 1; w2 < 4; ++w2) {
      if (sv[w2] > v || (sv[w2] == v && sidx[w2] < ix)) { v = sv[w2]; ix = sidx[w2]; }
    }
    bmax[blockIdx.x] = v;
    bidx[blockIdx.x] = ix;
  }
}

// Final argmax reduce + output column write + word gather + LN(h1)+h0 / LN(c1)+c0.
__global__ __launch_bounds__(512) void finalize(
    const float* __restrict__ bmax, const int* __restrict__ bidx,
    const float* __restrict__ totoken, const float* __restrict__ embed,
    const float* __restrict__ h1, const float* __restrict__ c1,
    const float* __restrict__ h0, const float* __restrict__ c0,
    const float* __restrict__ gh, const float* __restrict__ bh,
    const float* __restrict__ gc, const float* __restrict__ bc,
    float* __restrict__ word, float* __restrict__ x1h, float* __restrict__ x1c,
    float* __restrict__ out, int step) {
  __shared__ float sm[8];
  __shared__ int smi[8];
  __shared__ int s_idx;
  int t = threadIdx.x, lane = t & 63, wave = t >> 6;
  float v = bmax[t];
  int ix = bidx[t];
#pragma unroll
  for (int off = 32; off; off >>= 1) {
    float ov = __shfl_down(v, off, 64);
    int oi = __shfl_down(ix, off, 64);
    if (ov > v || (ov == v && oi < ix)) { v = ov; ix = oi; }
  }
  if (lane == 0) { sm[wave] = v; smi[wave] = ix; }
  __syncthreads();
  if (t == 0) {
    float bv = sm[0];
    int bi = smi[0];
#pragma unroll
    for (int w2 = 1; w2 < 8; ++w2) {
      if (sm[w2] > bv || (sm[w2] == bv && smi[w2] < bi)) { bv = sm[w2]; bi = smi[w2]; }
    }
    s_idx = bi;
  }
  __syncthreads();
  int idx = s_idx;
  float tv = totoken[idx];
  if (t < BDIM) out[t * TSTEPS + step] = tv;
  for (int k = t; k < HDIM; k += 512) word[k] = embed[(size_t)idx * HDIM + k];
  __syncthreads();  // sm about to be reused by allreduce
  // x1h = LN(h1)*gh+bh + h0
  float a0 = h1[t], a1 = h1[t + 512];
  float m = block_allreduce_sum<512>(a0 + a1, sm) * (1.f / 1024.f);
  float d0 = a0 - m, d1 = a1 - m;
  float var = block_allreduce_sum<512>(d0 * d0 + d1 * d1, sm) * (1.f / 1024.f);
  float inv = 1.f / sqrtf(var + 1e-5f);
  x1h[t] = d0 * inv * gh[t] + bh[t] + h0[t];
  x1h[t + 512] = d1 * inv * gh[t + 512] + bh[t + 512] + h0[t + 512];
  // x1c = LN(c1)*gc+bc + c0
  float b0 = c1[t], b1 = c1[t + 512];
  float mc = block_allreduce_sum<512>(b0 + b1, sm) * (1.f / 1024.f);
  float e0 = b0 - mc, e1 = b1 - mc;
  float vc = block_allreduce_sum<512>(e0 * e0 + e1 * e1, sm) * (1.f / 1024.f);
  float invc = 1.f / sqrtf(vc + 1e-5f);
  x1c[t] = e0 * invc * gc[t] + bc[t] + c0[t];
  x1c[t + 512] = e1 * invc * gc[t + 512] + bc[t + 512] + c0[t + 512];
}

extern "C" void kernel_launch(void* const* d_in, const int* in_sizes, int n_in,
                              void* d_out, int out_size, void* d_ws,
                              size_t ws_size, hipStream_t stream) {
  (void)in_sizes; (void)n_in; (void)out_size; (void)ws_size;
  const float* features = (const float*)d_in[0];
  const float* fc1_w    = (const float*)d_in[1];
  const float* fc1_b    = (const float*)d_in[2];
  const float* init_h_w = (const float*)d_in[3];
  const float* init_h_b = (const float*)d_in[4];
  const float* init_c_w = (const float*)d_in[5];
  const float* init_c_b = (const float*)d_in[6];
  const float* ln_h_g   = (const float*)d_in[7];
  const float* ln_h_b   = (const float*)d_in[8];
  const float* ln_c_g   = (const float*)d_in[9];
  const float* ln_c_b   = (const float*)d_in[10];
  const float* w_ih1    = (const float*)d_in[11];
  const float* w_hh1    = (const float*)d_in[12];
  const float* b_ih1    = (const float*)d_in[13];
  const float* b_hh1    = (const float*)d_in[14];
  const float* w_ih2    = (const float*)d_in[15];
  const float* w_hh2    = (const float*)d_in[16];
  const float* b_ih2    = (const float*)d_in[17];
  const float* b_hh2    = (const float*)d_in[18];
  const float* fc_w     = (const float*)d_in[19];
  const float* fc_b     = (const float*)d_in[20];
  const float* embed_w  = (const float*)d_in[21];
  const float* totoken  = (const float*)d_in[22];
  // d_in[23] = max_length (15), hard-coded as TSTEPS.

  float* ws = (float*)d_ws;
  float* feat = ws + 0;
  float* preh = ws + 1024;
  float* prec = ws + 2048;
  float* h0   = ws + 3072;
  float* c0   = ws + 4096;
  float* h1   = ws + 5120;
  float* c1   = ws + 6144;
  float* h2b[2] = {ws + 7168, ws + 8192};
  float* c2b[2] = {ws + 9216, ws + 10240};
  float* h3b[2] = {ws + 11264, ws + 12288};
  float* c3b[2] = {ws + 13312, ws + 14336};
  float* x1h  = ws + 15360;
  float* x1c  = ws + 16384;
  float* word = ws + 17408;
  float* bmax = ws + 18432;
  int*   bidx = (int*)(ws + 18432 + FC_BLOCKS);
  float* out  = (float*)d_out;

  // feat = relu(features[0] @ fc1_w.T + fc1_b)
  gemv_relu<<<HDIM, 256, 0, stream>>>(fc1_w, features, fc1_b, feat, EDIM);
  // pre_h / pre_c
  gemv_relu<<<HDIM, 256, 0, stream>>>(init_h_w, feat, init_h_b, preh, HDIM);
  gemv_relu<<<HDIM, 256, 0, stream>>>(init_c_w, feat, init_c_b, prec, HDIM);
  ln2_kernel<<<1, 1024, 0, stream>>>(preh, prec, ln_h_g, ln_h_b, ln_c_g, ln_c_b,
                                     h0, c0);
  // step 0
  lstm_cell<<<HDIM, 256, 0, stream>>>(feat, h0, c0, w_ih1, w_hh1, b_ih1, b_hh1,
                                      h1, c1);
  lstm_cell<<<HDIM, 256, 0, stream>>>(h1, h0, c0, w_ih2, w_hh2, b_ih2, b_hh2,
                                      h2b[0], c2b[0]);
  lstm_cell<<<HDIM, 256, 0, stream>>>(h2b[0], h0, c0, w_ih2, w_hh2, b_ih2,
                                      b_hh2, h3b[0], c3b[0]);
  fc_argmax_part<<<FC_BLOCKS, 256, 0, stream>>>(fc_w, fc_b, h3b[0], bmax, bidx);
  finalize<<<1, 512, 0, stream>>>(bmax, bidx, totoken, embed_w, h1, c1, h0, c0,
                                  ln_h_g, ln_h_b, ln_c_g, ln_c_b, word, x1h,
                                  x1c, out, 0);
  int cur = 0;
  for (int t = 1; t < TSTEPS; ++t) {
    int nxt = cur ^ 1;
    lstm_cell<<<HDIM, 256, 0, stream>>>(word, x1h, x1c, w_ih1, w_hh1, b_ih1,
                                        b_hh1, h1, c1);
    lstm_cell<<<HDIM, 256, 0, stream>>>(h1, h2b[cur], c2b[cur], w_ih2, w_hh2,
                                        b_ih2, b_hh2, h2b[nxt], c2b[nxt]);
    lstm_cell<<<HDIM, 256, 0, stream>>>(h2b[nxt], h3b[cur], c3b[cur], w_ih2,
                                        w_hh2, b_ih2, b_hh2, h3b[nxt],
                                        c3b[nxt]);
    fc_argmax_part<<<FC_BLOCKS, 256, 0, stream>>>(fc_w, fc_b, h3b[nxt], bmax,
                                                  bidx);
    finalize<<<1, 512, 0, stream>>>(bmax, bidx, totoken, embed_w, h1, c1, h0,
                                    c0, ln_h_g, ln_h_b, ln_c_g, ln_c_b, word,
                                    x1h, x1c, out, t);
    cur = nxt;
  }
}